// Round 8
// baseline (415.756 us; speedup 1.0000x reference)
//
#include <hip/hip_runtime.h>
#include <math.h>
#include <stdint.h>

typedef unsigned short u16;
typedef unsigned int u32;
typedef __attribute__((ext_vector_type(8))) __bf16 bf16x8;
typedef __attribute__((ext_vector_type(4))) float f32x4;

#define AS1 __attribute__((address_space(1)))
#define AS3 __attribute__((address_space(3)))

__device__ __forceinline__ void stage16(const void* g, void* l) {
    __builtin_amdgcn_global_load_lds((const AS1 void*)(uintptr_t)g,
                                     (AS3 void*)(uintptr_t)l, 16, 0, 0);
}

__device__ __forceinline__ u16 f2bf(float f) {
    u32 u = __float_as_uint(f);
    u += 0x7fffu + ((u >> 16) & 1u);
    return (u16)(u >> 16);
}

// ---------------- LayerNorm: 256 thr per row of 768, bf16 out ----------------
__global__ __launch_bounds__(256) void ln_kernel(const float* __restrict__ x,
                                                 const float* __restrict__ g,
                                                 const float* __restrict__ b,
                                                 u16* __restrict__ out) {
    int row = blockIdx.x;
    int tid = threadIdx.x;
    const float* xr = x + (size_t)row * 768;
    float x0 = xr[tid], x1 = xr[tid + 256], x2 = xr[tid + 512];

    __shared__ float red[256];
    red[tid] = x0 + x1 + x2;
    __syncthreads();
    for (int off = 128; off > 0; off >>= 1) {
        if (tid < off) red[tid] += red[tid + off];
        __syncthreads();
    }
    float mu = red[0] * (1.0f / 768.0f);
    __syncthreads();

    float d0 = x0 - mu, d1 = x1 - mu, d2 = x2 - mu;
    red[tid] = d0 * d0 + d1 * d1 + d2 * d2;
    __syncthreads();
    for (int off = 128; off > 0; off >>= 1) {
        if (tid < off) red[tid] += red[tid + off];
        __syncthreads();
    }
    float var = red[0] * (1.0f / 768.0f);
    float rs = rsqrtf(var + 1e-5f);

    u16* orow = out + (size_t)row * 768;
    orow[tid]       = f2bf(d0 * rs * g[tid]       + b[tid]);
    orow[tid + 256] = f2bf(d1 * rs * g[tid + 256] + b[tid + 256]);
    orow[tid + 512] = f2bf(d2 * rs * g[tid + 512] + b[tid + 512]);
}

// ---------------- transpose + fp32->bf16 convert: W[K][N] -> Wt[N][K] ----------------
__global__ __launch_bounds__(256) void transpose_bf16(const float* __restrict__ W,
                                                      u16* __restrict__ Wt,
                                                      int K, int N) {
    __shared__ float t[32][33];
    int tx = threadIdx.x, ty = threadIdx.y;
    int n0 = blockIdx.x * 32, k0 = blockIdx.y * 32;
#pragma unroll
    for (int j = 0; j < 32; j += 8)
        t[ty + j][tx] = W[(size_t)(k0 + ty + j) * N + n0 + tx];
    __syncthreads();
#pragma unroll
    for (int j = 0; j < 32; j += 8)
        Wt[(size_t)(n0 + ty + j) * K + k0 + tx] = f2bf(t[tx][ty + j]);
}

// ---------------- V transpose: qkv v-region [8192][2304] -> Vt[96][64][1024] ----------------
__global__ __launch_bounds__(256) void vt_kernel(const u16* __restrict__ qkv,
                                                 u16* __restrict__ Vt) {
    __shared__ u16 t[32][34];
    const int tx = threadIdx.x, ty = threadIdx.y;
    const int s0 = blockIdx.x * 32, d0 = blockIdx.y * 32, bh = blockIdx.z;
    const int b = bh / 12, h = bh % 12;
#pragma unroll
    for (int j = 0; j < 32; j += 8)
        t[ty + j][tx] = qkv[((size_t)(b * 1024) + s0 + ty + j) * 2304 + 1536 + h * 64 + d0 + tx];
    __syncthreads();
#pragma unroll
    for (int j = 0; j < 32; j += 8)
        Vt[((size_t)bh * 64 + d0 + ty + j) * 1024 + s0 + tx] = t[tx][ty + j];
}

// ---------------- bf16 MFMA GEMM, templated tile, dbuf BK=64, 2-phase counted ----------------
// A: [M][K] bf16 row-major. Bt: [N][K] bf16 row-major (BM==BN assumed).
// Waves arranged WR x WC; wave tile (BM/WR) x (BN/WC). LDS rows 128B,
// byte ^= (row&7)<<4 swizzle (measured zero-conflict); staging pre-swizzles the
// GLOBAL source address since global_load_lds writes linearly.
// Pipeline: stage(t+1) issued FIRST, long MFMA phase on buf(t), then ONE
// vmcnt(0)+barrier per K-tile (drain lands after the compute phase -> cheap).
template <int BM, int BN, int WR, int WC>
__global__ __launch_bounds__(WR * WC * 64, 1024 / (WR * WC * 64)) void gemm_pipe(
    const u16* __restrict__ A, const u16* __restrict__ Bt,
    const float* __restrict__ bias, const float* __restrict__ res,
    float* __restrict__ outF, u16* __restrict__ outB,
    int N, int K, int act) {
    constexpr int THREADS = WR * WC * 64;
    constexpr int MI = BM / WR / 16;   // A fragments per wave
    constexpr int NI = BN / WC / 16;   // B fragments per wave
    constexpr int TILE = BM * 128;     // bytes per operand tile (BK=64)
    constexpr int RND = TILE / (THREADS * 16);
    __shared__ char lds[2 * 2 * TILE];

    const int tid = threadIdx.x, lane = tid & 63, wid = tid >> 6;
    const int l15 = lane & 15, lk = lane >> 4;
    const int wr = wid / WC, wc = wid % WC;

    // bijective XCD swizzle (all launch grids have nwg % 8 == 0)
    int wg = blockIdx.y * gridDim.x + blockIdx.x;
    const int nwg = gridDim.x * gridDim.y;
    wg = (wg & 7) * (nwg >> 3) + (wg >> 3);
    const int brow = (wg / gridDim.x) * BM;
    const int bcol = (wg % gridDim.x) * BN;

    const size_t K2 = (size_t)K * 2;
    const char* Abase = (const char*)A + (size_t)brow * K2;
    const char* Bbase = (const char*)Bt + (size_t)bcol * K2;

    int srow[RND], scol[RND];
#pragma unroll
    for (int j = 0; j < RND; ++j) {
        const int L = j * THREADS * 16 + tid * 16;
        srow[j] = L >> 7;
        scol[j] = (L & 127) ^ ((srow[j] & 7) << 4);
    }

    const int nt = K >> 6;

    auto stage_tile = [&](int t, char* dst) {
#pragma unroll
        for (int j = 0; j < RND; ++j) {
            const size_t off = (size_t)srow[j] * K2 + (size_t)t * 128 + scol[j];
            stage16(Abase + off, dst + j * THREADS * 16 + tid * 16);
            stage16(Bbase + off, dst + TILE + j * THREADS * 16 + tid * 16);
        }
    };

    f32x4 acc[MI][NI] = {};

    stage_tile(0, lds);
    asm volatile("s_waitcnt vmcnt(0)\n\ts_barrier" ::: "memory");

    for (int t = 0; t < nt; ++t) {
        if (t + 1 < nt) stage_tile(t + 1, lds + ((t + 1) & 1) * 2 * TILE);

        const char* As = lds + (t & 1) * 2 * TILE;
        const char* Bs = As + TILE;
#pragma unroll
        for (int kc = 0; kc < 2; ++kc) {
            bf16x8 af[MI], bfv[NI];
#pragma unroll
            for (int m = 0; m < MI; ++m) {
                const int row = wr * (BM / WR) + m * 16 + l15;
                af[m] = *(const bf16x8*)(As + row * 128 +
                                         ((kc * 64 + lk * 16) ^ ((row & 7) << 4)));
            }
#pragma unroll
            for (int n = 0; n < NI; ++n) {
                const int row = wc * (BN / WC) + n * 16 + l15;
                bfv[n] = *(const bf16x8*)(Bs + row * 128 +
                                          ((kc * 64 + lk * 16) ^ ((row & 7) << 4)));
            }
            __builtin_amdgcn_s_setprio(1);
#pragma unroll
            for (int m = 0; m < MI; ++m)
#pragma unroll
                for (int n = 0; n < NI; ++n)
                    acc[m][n] = __builtin_amdgcn_mfma_f32_16x16x32_bf16(af[m], bfv[n], acc[m][n], 0, 0, 0);
            __builtin_amdgcn_s_setprio(0);
        }
        if (t + 1 < nt)
            asm volatile("s_waitcnt vmcnt(0)\n\ts_barrier" ::: "memory");
    }

#pragma unroll
    for (int m = 0; m < MI; ++m)
#pragma unroll
        for (int n = 0; n < NI; ++n)
#pragma unroll
            for (int r = 0; r < 4; ++r) {
                int row = brow + wr * (BM / WR) + m * 16 + lk * 4 + r;
                int col = bcol + wc * (BN / WC) + n * 16 + l15;
                float v = acc[m][n][r];
                if (bias) v += bias[col];
                if (act) v = 0.5f * v * (1.0f + erff(v * 0.70710678118654752f));
                if (res) v += res[(size_t)row * N + col];
                if (outB) outB[(size_t)row * N + col] = f2bf(v);
                else outF[(size_t)row * N + col] = v;
            }
}

// ---------------- MFMA flash attention, pipelined gload_lds staging ----------------
// qkv bf16 [8192][2304]; Vt bf16 [96][64][1024].
// Block: 64 q-rows x one (b,h). 4 waves, wave w owns q-rows 16w..16w+15.
// LDS: dbuf { K [64s][64d] 8KB + Vt [64d][64s] 8KB } x2 = 32KB, P 4x2KB = 40KB.
__global__ __launch_bounds__(256) void attn_mfma(const u16* __restrict__ qkv,
                                                 const u16* __restrict__ Vt,
                                                 u16* __restrict__ obf) {
    __shared__ char lds[40960];
    const int tid = threadIdx.x, lane = tid & 63, w = tid >> 6;
    const int g = lane >> 4, l15 = lane & 15;

    int wg = blockIdx.y * gridDim.x + blockIdx.x;
    const int nwg = gridDim.x * gridDim.y;
    wg = (wg & 7) * (nwg >> 3) + (wg >> 3);
    const int qb = 15 - (wg & 15);          // heavy tiles first within each chunk
    const int bh = wg >> 4;
    const int h = bh % 12, b = bh / 12;
    const int t0 = qb * 64;
    const float scale = 0.03608439182435161f;  // 768^-0.5 (C, not hs, per reference)

    // Q fragments (A-operand) in registers
    const size_t qrow = ((size_t)b * 1024 + t0 + 16 * w + l15) * 2304 + h * 64;
    const bf16x8 qf0 = *(const bf16x8*)(qkv + qrow + 8 * g);
    const bf16x8 qf1 = *(const bf16x8*)(qkv + qrow + 8 * g + 32);

    // staging source pointers (pre-swizzled): this thread covers rows r0, r0+8
    const int sub = ((lane & 7) * 16) ^ ((lane >> 3) << 4);
    const int r0 = 16 * w + (lane >> 3);
    const char* kSrc = (const char*)qkv + ((size_t)(b * 1024 + r0) * 2304 + 768 + h * 64) * 2 + sub;
    const char* vSrc = (const char*)Vt + ((size_t)(bh * 64 + r0) * 1024) * 2 + sub;
    const int dstOff = 2 * w * 1024 + lane * 16;

    // prologue: stage tile 0 into buf 0, drain
    stage16(kSrc,            lds + dstOff);
    stage16(kSrc + 8 * 4608, lds + dstOff + 1024);
    stage16(vSrc,            lds + 8192 + dstOff);
    stage16(vSrc + 8 * 2048, lds + 8192 + dstOff + 1024);
    kSrc += 64 * 4608; vSrc += 128;
    __syncthreads();

    const int swzA = (l15 & 7) << 4;
    float m_r[4] = {-1e30f, -1e30f, -1e30f, -1e30f};
    float l_r[4] = {0.f, 0.f, 0.f, 0.f};
    f32x4 oacc[4] = {};
    char* Pw = lds + 32768 + w * 2048;

    for (int c = 0; c <= qb; ++c) {
        if (c < qb) {
            char* dst = lds + ((c + 1) & 1) * 16384;
            stage16(kSrc,            dst + dstOff);
            stage16(kSrc + 8 * 4608, dst + dstOff + 1024);
            stage16(vSrc,            dst + 8192 + dstOff);
            stage16(vSrc + 8 * 2048, dst + 8192 + dstOff + 1024);
            kSrc += 64 * 4608; vSrc += 128;
            asm volatile("s_waitcnt vmcnt(4)\n\ts_barrier" ::: "memory");
        } else {
            asm volatile("s_waitcnt vmcnt(0)\n\ts_barrier" ::: "memory");
        }
        __builtin_amdgcn_sched_barrier(0);

        const char* bufK = lds + (c & 1) * 16384;
        const char* bufV = bufK + 8192;

        // S = Q K^T : D[q=4g+r][s=l15+16st]
        f32x4 sacc[4] = {};
#pragma unroll
        for (int st = 0; st < 4; ++st) {
            const char* krow = bufK + (l15 + 16 * st) * 128;
            const bf16x8 kf0 = *(const bf16x8*)(krow + ((16 * g) ^ swzA));
            const bf16x8 kf1 = *(const bf16x8*)(krow + ((16 * g + 64) ^ swzA));
            sacc[st] = __builtin_amdgcn_mfma_f32_16x16x32_bf16(qf0, kf0, sacc[st], 0, 0, 0);
            sacc[st] = __builtin_amdgcn_mfma_f32_16x16x32_bf16(qf1, kf1, sacc[st], 0, 0, 0);
        }

        const bool diag = (c == qb);
#pragma unroll
        for (int r = 0; r < 4; ++r) {
            float sv0 = sacc[0][r] * scale, sv1 = sacc[1][r] * scale;
            float sv2 = sacc[2][r] * scale, sv3 = sacc[3][r] * scale;
            if (diag) {
                const int trel = 16 * w + 4 * g + r;
                if (l15 +  0 > trel) sv0 = -1e30f;
                if (l15 + 16 > trel) sv1 = -1e30f;
                if (l15 + 32 > trel) sv2 = -1e30f;
                if (l15 + 48 > trel) sv3 = -1e30f;
            }
            float mx = fmaxf(fmaxf(sv0, sv1), fmaxf(sv2, sv3));
#pragma unroll
            for (int off = 1; off < 16; off <<= 1) mx = fmaxf(mx, __shfl_xor(mx, off));
            const float mnew = fmaxf(m_r[r], mx);
            const float corr = __expf(m_r[r] - mnew);
            const float p0 = __expf(sv0 - mnew), p1 = __expf(sv1 - mnew);
            const float p2 = __expf(sv2 - mnew), p3 = __expf(sv3 - mnew);
            float ps = p0 + p1 + p2 + p3;
#pragma unroll
            for (int off = 1; off < 16; off <<= 1) ps += __shfl_xor(ps, off);
            l_r[r] = l_r[r] * corr + ps;
            m_r[r] = mnew;
            oacc[0][r] *= corr; oacc[1][r] *= corr;
            oacc[2][r] *= corr; oacc[3][r] *= corr;
            const int q = 4 * g + r;
            char* pr = Pw + q * 128;
            const int sw = (q & 7) << 4;
            *(u16*)(pr + ((l15 * 2 +  0) ^ sw)) = f2bf(p0);
            *(u16*)(pr + ((l15 * 2 + 32) ^ sw)) = f2bf(p1);
            *(u16*)(pr + ((l15 * 2 + 64) ^ sw)) = f2bf(p2);
            *(u16*)(pr + ((l15 * 2 + 96) ^ sw)) = f2bf(p3);
        }

        // O += P V : A = P[16q][32s-chunk], B = Vt rows (d-major)
#pragma unroll
        for (int kc = 0; kc < 2; ++kc) {
            const bf16x8 pa = *(const bf16x8*)(Pw + l15 * 128 + ((16 * g + 64 * kc) ^ swzA));
#pragma unroll
            for (int dt = 0; dt < 4; ++dt) {
                const int d = l15 + 16 * dt;
                const bf16x8 vf = *(const bf16x8*)(bufV + d * 128 +
                                   ((16 * g + 64 * kc) ^ ((d & 7) << 4)));
                oacc[dt] = __builtin_amdgcn_mfma_f32_16x16x32_bf16(pa, vf, oacc[dt], 0, 0, 0);
            }
        }
        asm volatile("s_barrier" ::: "memory");  // buffers safe to overwrite
    }

    const size_t orow0 = ((size_t)b * 1024 + t0 + 16 * w) * 768 + h * 64;
#pragma unroll
    for (int r = 0; r < 4; ++r) {
        const float inv = 1.0f / l_r[r];
        const size_t orow = orow0 + (size_t)(4 * g + r) * 768;
#pragma unroll
        for (int dt = 0; dt < 4; ++dt)
            obf[orow + 16 * dt + l15] = f2bf(oacc[dt][r] * inv);
    }
}

extern "C" void kernel_launch(void* const* d_in, const int* in_sizes, int n_in,
                              void* d_out, int out_size, void* d_ws, size_t ws_size,
                              hipStream_t stream) {
    const float* x   = (const float*)d_in[0];
    const float* Wq  = (const float*)d_in[1];
    const float* Wk  = (const float*)d_in[2];
    const float* Wv  = (const float*)d_in[3];
    const float* Wo  = (const float*)d_in[4];
    const float* bo  = (const float*)d_in[5];
    const float* W1  = (const float*)d_in[6];
    const float* b1  = (const float*)d_in[7];
    const float* W2  = (const float*)d_in[8];
    const float* b2  = (const float*)d_in[9];
    const float* g1  = (const float*)d_in[10];
    const float* be1 = (const float*)d_in[11];
    const float* g2  = (const float*)d_in[12];
    const float* be2 = (const float*)d_in[13];
    float* out = (float*)d_out;

    char* ws = (char*)d_ws;
    u16* qkv_bf = (u16*)(ws);              // [8192][2304] bf16  37.7MB (dead after attn)
    u16* ff1_bf = (u16*)(ws);              // [8192][3072] bf16  50.3MB (reuses qkv region)
    float* x2   = (float*)(ws + 50331648); // [8192][768]  f32   25.2MB
    u16* h_bf   = (u16*)(ws + 75497472);   // [8192][768]  bf16  12.6MB
    u16* o_bf   = (u16*)(ws + 88080384);   // [8192][768]  bf16  12.6MB
    u16* Wqkvt  = (u16*)(ws + 100663296);  // [2304][768]  bf16   3.5MB
    u16* W1t    = (u16*)(ws + 104202240);  // [3072][768]  bf16   4.7MB
    u16* W2t    = (u16*)(ws + 108920832);  // [768][3072]  bf16   4.7MB
    u16* Wot    = (u16*)(ws + 113639424);  // [768][768]   bf16   1.2MB
    u16* Vt     = (u16*)(ws + 114819072);  // [96][64][1024] bf16 12.6MB (dead after attn)

    dim3 tb(32, 8);
    transpose_bf16<<<dim3(24, 24), tb, 0, stream>>>(Wq, Wqkvt, 768, 768);
    transpose_bf16<<<dim3(24, 24), tb, 0, stream>>>(Wk, Wqkvt + 768 * 768, 768, 768);
    transpose_bf16<<<dim3(24, 24), tb, 0, stream>>>(Wv, Wqkvt + 2 * 768 * 768, 768, 768);
    transpose_bf16<<<dim3(24, 24), tb, 0, stream>>>(Wo, Wot, 768, 768);
    transpose_bf16<<<dim3(96, 24), tb, 0, stream>>>(W1, W1t, 768, 3072);
    transpose_bf16<<<dim3(24, 96), tb, 0, stream>>>(W2, W2t, 3072, 768);

    // h = LN1(x)
    ln_kernel<<<8192, 256, 0, stream>>>(x, g1, be1, h_bf);
    // qkv = h @ [Wq|Wk|Wv]  (bf16 out) — 256^2 tile, 8 waves
    gemm_pipe<256, 256, 2, 4><<<dim3(9, 32), 512, 0, stream>>>(h_bf, Wqkvt, nullptr, nullptr, nullptr, qkv_bf, 2304, 768, 0);
    // Vt = per-head transpose of V
    vt_kernel<<<dim3(32, 2, 96), tb, 0, stream>>>(qkv_bf, Vt);
    // o = causal-softmax(q k^T * 768^-.5) v  (bf16 out)
    attn_mfma<<<dim3(16, 96), 256, 0, stream>>>(qkv_bf, Vt, o_bf);
    // x2 = x + o @ Wo + bo — 128^2 tile, 4 waves
    gemm_pipe<128, 128, 2, 2><<<dim3(6, 64), 256, 0, stream>>>(o_bf, Wot, bo, x, x2, nullptr, 768, 768, 0);
    // h = LN2(x2)
    ln_kernel<<<8192, 256, 0, stream>>>(x2, g2, be2, h_bf);
    // ff1 = gelu(h @ W1 + b1)  (bf16 out) — 256^2 tile
    gemm_pipe<256, 256, 2, 4><<<dim3(12, 32), 512, 0, stream>>>(h_bf, W1t, b1, nullptr, nullptr, ff1_bf, 3072, 768, 1);
    // out = x2 + ff1 @ W2 + b2 — 128^2 tile
    gemm_pipe<128, 128, 2, 2><<<dim3(6, 64), 256, 0, stream>>>(ff1_bf, W2t, b2, x2, out, nullptr, 768, 3072, 0);
}

// Round 9
// 373.925 us; speedup vs baseline: 1.1119x; 1.1119x over previous
//
#include <hip/hip_runtime.h>
#include <math.h>
#include <stdint.h>

typedef unsigned short u16;
typedef unsigned int u32;
typedef __attribute__((ext_vector_type(8))) __bf16 bf16x8;
typedef __attribute__((ext_vector_type(4))) float f32x4;

#define AS1 __attribute__((address_space(1)))
#define AS3 __attribute__((address_space(3)))

__device__ __forceinline__ void stage16(const void* g, void* l) {
    __builtin_amdgcn_global_load_lds((const AS1 void*)(uintptr_t)g,
                                     (AS3 void*)(uintptr_t)l, 16, 0, 0);
}

__device__ __forceinline__ u16 f2bf(float f) {
    u32 u = __float_as_uint(f);
    u += 0x7fffu + ((u >> 16) & 1u);
    return (u16)(u >> 16);
}

// ---------------- LayerNorm: 256 thr per row of 768, bf16 out ----------------
__global__ __launch_bounds__(256) void ln_kernel(const float* __restrict__ x,
                                                 const float* __restrict__ g,
                                                 const float* __restrict__ b,
                                                 u16* __restrict__ out) {
    int row = blockIdx.x;
    int tid = threadIdx.x;
    const float* xr = x + (size_t)row * 768;
    float x0 = xr[tid], x1 = xr[tid + 256], x2 = xr[tid + 512];

    __shared__ float red[256];
    red[tid] = x0 + x1 + x2;
    __syncthreads();
    for (int off = 128; off > 0; off >>= 1) {
        if (tid < off) red[tid] += red[tid + off];
        __syncthreads();
    }
    float mu = red[0] * (1.0f / 768.0f);
    __syncthreads();

    float d0 = x0 - mu, d1 = x1 - mu, d2 = x2 - mu;
    red[tid] = d0 * d0 + d1 * d1 + d2 * d2;
    __syncthreads();
    for (int off = 128; off > 0; off >>= 1) {
        if (tid < off) red[tid] += red[tid + off];
        __syncthreads();
    }
    float var = red[0] * (1.0f / 768.0f);
    float rs = rsqrtf(var + 1e-5f);

    u16* orow = out + (size_t)row * 768;
    orow[tid]       = f2bf(d0 * rs * g[tid]       + b[tid]);
    orow[tid + 256] = f2bf(d1 * rs * g[tid + 256] + b[tid + 256]);
    orow[tid + 512] = f2bf(d2 * rs * g[tid + 512] + b[tid + 512]);
}

// ---------------- transpose + fp32->bf16 convert: W[K][N] -> Wt[N][K] ----------------
__global__ __launch_bounds__(256) void transpose_bf16(const float* __restrict__ W,
                                                      u16* __restrict__ Wt,
                                                      int K, int N) {
    __shared__ float t[32][33];
    int tx = threadIdx.x, ty = threadIdx.y;
    int n0 = blockIdx.x * 32, k0 = blockIdx.y * 32;
#pragma unroll
    for (int j = 0; j < 32; j += 8)
        t[ty + j][tx] = W[(size_t)(k0 + ty + j) * N + n0 + tx];
    __syncthreads();
#pragma unroll
    for (int j = 0; j < 32; j += 8)
        Wt[(size_t)(n0 + ty + j) * K + k0 + tx] = f2bf(t[tx][ty + j]);
}

// ---------------- V transpose: qkv v-region [8192][2304] -> Vt[96][64][1024] ----------------
__global__ __launch_bounds__(256) void vt_kernel(const u16* __restrict__ qkv,
                                                 u16* __restrict__ Vt) {
    __shared__ u16 t[32][34];
    const int tx = threadIdx.x, ty = threadIdx.y;
    const int s0 = blockIdx.x * 32, d0 = blockIdx.y * 32, bh = blockIdx.z;
    const int b = bh / 12, h = bh % 12;
#pragma unroll
    for (int j = 0; j < 32; j += 8)
        t[ty + j][tx] = qkv[((size_t)(b * 1024) + s0 + ty + j) * 2304 + 1536 + h * 64 + d0 + tx];
    __syncthreads();
#pragma unroll
    for (int j = 0; j < 32; j += 8)
        Vt[((size_t)bh * 64 + d0 + ty + j) * 1024 + s0 + tx] = t[tx][ty + j];
}

// ---------------- bf16 MFMA GEMM: 128^2, BK=32, TRIPLE buffer, 2-deep prefetch ----------------
// A: [M][K] bf16 row-major. Bt: [N][K] bf16 row-major.
// 4 waves (2x2), wave = 64x64. LDS 3 x (A 8KB + B 8KB) = 48KB -> 3 blocks/CU.
// Rows 64B; byte-in-row XOR by ((row>>1)&3)<<4: a 16-row fragment read tiles all
// 32 banks exactly 2-way (free, m136). Staging pre-swizzles the GLOBAL source
// (global_load_lds writes linearly). Pipeline: tile t's loads issued 2 K-steps
// ahead; per iter ONE "vmcnt(4); s_barrier" (t landed, t+1 in flight) then
// stage(t+2) into the buffer last read at t-1 (WAR-safe via the barrier).
__global__ __launch_bounds__(256, 3) void gemm_k32(
    const u16* __restrict__ A, const u16* __restrict__ Bt,
    const float* __restrict__ bias, const float* __restrict__ res,
    float* __restrict__ outF, u16* __restrict__ outB,
    int N, int K, int act) {
    __shared__ char lds[49152];
    const int tid = threadIdx.x, lane = tid & 63, wid = tid >> 6;
    const int l15 = lane & 15, lk = lane >> 4;
    const int wrow = (wid >> 1) * 64, wcol = (wid & 1) * 64;

    // bijective XCD swizzle (all launch grids have nwg % 8 == 0)
    int wg = blockIdx.y * gridDim.x + blockIdx.x;
    const int nwg = gridDim.x * gridDim.y;
    wg = (wg & 7) * (nwg >> 3) + (wg >> 3);
    const int brow = (wg / gridDim.x) * 128;
    const int bcol = (wg % gridDim.x) * 128;

    const size_t K2 = (size_t)K * 2;
    const char* Abase = (const char*)A + (size_t)brow * K2;
    const char* Bbase = (const char*)Bt + (size_t)bcol * K2;

    // staging geometry: per operand tile 8KB = 2 rounds x 256 thr x 16B.
    // LDS linear L = j*4096 + tid*16; row = L>>6, src col = (L&63)^(((row>>1)&3)<<4)
    int srow[2], scol[2];
#pragma unroll
    for (int j = 0; j < 2; ++j) {
        const int L = j * 4096 + tid * 16;
        srow[j] = L >> 6;
        scol[j] = (L & 63) ^ (((srow[j] >> 1) & 3) << 4);
    }

    const int nt = K >> 5;

    auto stage_tile = [&](int t, char* dst) {
#pragma unroll
        for (int j = 0; j < 2; ++j) {
            const size_t off = (size_t)srow[j] * K2 + (size_t)t * 64 + scol[j];
            stage16(Abase + off, dst + j * 4096 + tid * 16);
            stage16(Bbase + off, dst + 8192 + j * 4096 + tid * 16);
        }
    };

    f32x4 acc[4][4] = {};

    // prologue: tiles 0 and 1 in flight
    stage_tile(0, lds);
    stage_tile(1, lds + 16384);

    for (int t = 0; t < nt; ++t) {
        // land tile t; tile t+1's 4 loads stay in flight
        if (t + 1 < nt) asm volatile("s_waitcnt vmcnt(4)\n\ts_barrier" ::: "memory");
        else            asm volatile("s_waitcnt vmcnt(0)\n\ts_barrier" ::: "memory");
        __builtin_amdgcn_sched_barrier(0);

        if (t + 2 < nt) stage_tile(t + 2, lds + ((t + 2) % 3) * 16384);

        const char* As = lds + (t % 3) * 16384;
        const char* Bs = As + 8192;
        bf16x8 af[4], bfv[4];
#pragma unroll
        for (int m = 0; m < 4; ++m) {
            const int row = wrow + m * 16 + l15;
            af[m] = *(const bf16x8*)(As + row * 64 +
                                     ((lk * 16) ^ (((row >> 1) & 3) << 4)));
        }
#pragma unroll
        for (int n = 0; n < 4; ++n) {
            const int row = wcol + n * 16 + l15;
            bfv[n] = *(const bf16x8*)(Bs + row * 64 +
                                      ((lk * 16) ^ (((row >> 1) & 3) << 4)));
        }
        __builtin_amdgcn_s_setprio(1);
#pragma unroll
        for (int m = 0; m < 4; ++m)
#pragma unroll
            for (int n = 0; n < 4; ++n)
                acc[m][n] = __builtin_amdgcn_mfma_f32_16x16x32_bf16(af[m], bfv[n], acc[m][n], 0, 0, 0);
        __builtin_amdgcn_s_setprio(0);
        // no bottom barrier: next iteration's vmcnt+barrier provides the WAR fence
    }

#pragma unroll
    for (int m = 0; m < 4; ++m)
#pragma unroll
        for (int n = 0; n < 4; ++n)
#pragma unroll
            for (int r = 0; r < 4; ++r) {
                int row = brow + wrow + m * 16 + lk * 4 + r;
                int col = bcol + wcol + n * 16 + l15;
                float v = acc[m][n][r];
                if (bias) v += bias[col];
                if (act) v = 0.5f * v * (1.0f + erff(v * 0.70710678118654752f));
                if (res) v += res[(size_t)row * N + col];
                if (outB) outB[(size_t)row * N + col] = f2bf(v);
                else outF[(size_t)row * N + col] = v;
            }
}

// ---------------- MFMA flash attention, pipelined gload_lds staging ----------------
// qkv bf16 [8192][2304]; Vt bf16 [96][64][1024].
// Block: 64 q-rows x one (b,h). 4 waves, wave w owns q-rows 16w..16w+15.
// LDS: dbuf { K [64s][64d] 8KB + Vt [64d][64s] 8KB } x2 = 32KB, P 4x2KB = 40KB.
__global__ __launch_bounds__(256) void attn_mfma(const u16* __restrict__ qkv,
                                                 const u16* __restrict__ Vt,
                                                 u16* __restrict__ obf) {
    __shared__ char lds[40960];
    const int tid = threadIdx.x, lane = tid & 63, w = tid >> 6;
    const int g = lane >> 4, l15 = lane & 15;

    int wg = blockIdx.y * gridDim.x + blockIdx.x;
    const int nwg = gridDim.x * gridDim.y;
    wg = (wg & 7) * (nwg >> 3) + (wg >> 3);
    const int qb = 15 - (wg & 15);          // heavy tiles first within each chunk
    const int bh = wg >> 4;
    const int h = bh % 12, b = bh / 12;
    const int t0 = qb * 64;
    const float scale = 0.03608439182435161f;  // 768^-0.5 (C, not hs, per reference)

    // Q fragments (A-operand) in registers
    const size_t qrow = ((size_t)b * 1024 + t0 + 16 * w + l15) * 2304 + h * 64;
    const bf16x8 qf0 = *(const bf16x8*)(qkv + qrow + 8 * g);
    const bf16x8 qf1 = *(const bf16x8*)(qkv + qrow + 8 * g + 32);

    // staging source pointers (pre-swizzled): this thread covers rows r0, r0+8
    const int sub = ((lane & 7) * 16) ^ ((lane >> 3) << 4);
    const int r0 = 16 * w + (lane >> 3);
    const char* kSrc = (const char*)qkv + ((size_t)(b * 1024 + r0) * 2304 + 768 + h * 64) * 2 + sub;
    const char* vSrc = (const char*)Vt + ((size_t)(bh * 64 + r0) * 1024) * 2 + sub;
    const int dstOff = 2 * w * 1024 + lane * 16;

    // prologue: stage tile 0 into buf 0, drain
    stage16(kSrc,            lds + dstOff);
    stage16(kSrc + 8 * 4608, lds + dstOff + 1024);
    stage16(vSrc,            lds + 8192 + dstOff);
    stage16(vSrc + 8 * 2048, lds + 8192 + dstOff + 1024);
    kSrc += 64 * 4608; vSrc += 128;
    __syncthreads();

    const int swzA = (l15 & 7) << 4;
    float m_r[4] = {-1e30f, -1e30f, -1e30f, -1e30f};
    float l_r[4] = {0.f, 0.f, 0.f, 0.f};
    f32x4 oacc[4] = {};
    char* Pw = lds + 32768 + w * 2048;

    for (int c = 0; c <= qb; ++c) {
        if (c < qb) {
            char* dst = lds + ((c + 1) & 1) * 16384;
            stage16(kSrc,            dst + dstOff);
            stage16(kSrc + 8 * 4608, dst + dstOff + 1024);
            stage16(vSrc,            dst + 8192 + dstOff);
            stage16(vSrc + 8 * 2048, dst + 8192 + dstOff + 1024);
            kSrc += 64 * 4608; vSrc += 128;
            asm volatile("s_waitcnt vmcnt(4)\n\ts_barrier" ::: "memory");
        } else {
            asm volatile("s_waitcnt vmcnt(0)\n\ts_barrier" ::: "memory");
        }
        __builtin_amdgcn_sched_barrier(0);

        const char* bufK = lds + (c & 1) * 16384;
        const char* bufV = bufK + 8192;

        // S = Q K^T : D[q=4g+r][s=l15+16st]
        f32x4 sacc[4] = {};
#pragma unroll
        for (int st = 0; st < 4; ++st) {
            const char* krow = bufK + (l15 + 16 * st) * 128;
            const bf16x8 kf0 = *(const bf16x8*)(krow + ((16 * g) ^ swzA));
            const bf16x8 kf1 = *(const bf16x8*)(krow + ((16 * g + 64) ^ swzA));
            sacc[st] = __builtin_amdgcn_mfma_f32_16x16x32_bf16(qf0, kf0, sacc[st], 0, 0, 0);
            sacc[st] = __builtin_amdgcn_mfma_f32_16x16x32_bf16(qf1, kf1, sacc[st], 0, 0, 0);
        }

        const bool diag = (c == qb);
#pragma unroll
        for (int r = 0; r < 4; ++r) {
            float sv0 = sacc[0][r] * scale, sv1 = sacc[1][r] * scale;
            float sv2 = sacc[2][r] * scale, sv3 = sacc[3][r] * scale;
            if (diag) {
                const int trel = 16 * w + 4 * g + r;
                if (l15 +  0 > trel) sv0 = -1e30f;
                if (l15 + 16 > trel) sv1 = -1e30f;
                if (l15 + 32 > trel) sv2 = -1e30f;
                if (l15 + 48 > trel) sv3 = -1e30f;
            }
            float mx = fmaxf(fmaxf(sv0, sv1), fmaxf(sv2, sv3));
#pragma unroll
            for (int off = 1; off < 16; off <<= 1) mx = fmaxf(mx, __shfl_xor(mx, off));
            const float mnew = fmaxf(m_r[r], mx);
            const float corr = __expf(m_r[r] - mnew);
            const float p0 = __expf(sv0 - mnew), p1 = __expf(sv1 - mnew);
            const float p2 = __expf(sv2 - mnew), p3 = __expf(sv3 - mnew);
            float ps = p0 + p1 + p2 + p3;
#pragma unroll
            for (int off = 1; off < 16; off <<= 1) ps += __shfl_xor(ps, off);
            l_r[r] = l_r[r] * corr + ps;
            m_r[r] = mnew;
            oacc[0][r] *= corr; oacc[1][r] *= corr;
            oacc[2][r] *= corr; oacc[3][r] *= corr;
            const int q = 4 * g + r;
            char* pr = Pw + q * 128;
            const int sw = (q & 7) << 4;
            *(u16*)(pr + ((l15 * 2 +  0) ^ sw)) = f2bf(p0);
            *(u16*)(pr + ((l15 * 2 + 32) ^ sw)) = f2bf(p1);
            *(u16*)(pr + ((l15 * 2 + 64) ^ sw)) = f2bf(p2);
            *(u16*)(pr + ((l15 * 2 + 96) ^ sw)) = f2bf(p3);
        }

        // O += P V : A = P[16q][32s-chunk], B = Vt rows (d-major)
#pragma unroll
        for (int kc = 0; kc < 2; ++kc) {
            const bf16x8 pa = *(const bf16x8*)(Pw + l15 * 128 + ((16 * g + 64 * kc) ^ swzA));
#pragma unroll
            for (int dt = 0; dt < 4; ++dt) {
                const int d = l15 + 16 * dt;
                const bf16x8 vf = *(const bf16x8*)(bufV + d * 128 +
                                   ((16 * g + 64 * kc) ^ ((d & 7) << 4)));
                oacc[dt] = __builtin_amdgcn_mfma_f32_16x16x32_bf16(pa, vf, oacc[dt], 0, 0, 0);
            }
        }
        asm volatile("s_barrier" ::: "memory");  // buffers safe to overwrite
    }

    const size_t orow0 = ((size_t)b * 1024 + t0 + 16 * w) * 768 + h * 64;
#pragma unroll
    for (int r = 0; r < 4; ++r) {
        const float inv = 1.0f / l_r[r];
        const size_t orow = orow0 + (size_t)(4 * g + r) * 768;
#pragma unroll
        for (int dt = 0; dt < 4; ++dt)
            obf[orow + 16 * dt + l15] = f2bf(oacc[dt][r] * inv);
    }
}

extern "C" void kernel_launch(void* const* d_in, const int* in_sizes, int n_in,
                              void* d_out, int out_size, void* d_ws, size_t ws_size,
                              hipStream_t stream) {
    const float* x   = (const float*)d_in[0];
    const float* Wq  = (const float*)d_in[1];
    const float* Wk  = (const float*)d_in[2];
    const float* Wv  = (const float*)d_in[3];
    const float* Wo  = (const float*)d_in[4];
    const float* bo  = (const float*)d_in[5];
    const float* W1  = (const float*)d_in[6];
    const float* b1  = (const float*)d_in[7];
    const float* W2  = (const float*)d_in[8];
    const float* b2  = (const float*)d_in[9];
    const float* g1  = (const float*)d_in[10];
    const float* be1 = (const float*)d_in[11];
    const float* g2  = (const float*)d_in[12];
    const float* be2 = (const float*)d_in[13];
    float* out = (float*)d_out;

    char* ws = (char*)d_ws;
    u16* qkv_bf = (u16*)(ws);              // [8192][2304] bf16  37.7MB (dead after attn)
    u16* ff1_bf = (u16*)(ws);              // [8192][3072] bf16  50.3MB (reuses qkv region)
    float* x2   = (float*)(ws + 50331648); // [8192][768]  f32   25.2MB
    u16* h_bf   = (u16*)(ws + 75497472);   // [8192][768]  bf16  12.6MB
    u16* o_bf   = (u16*)(ws + 88080384);   // [8192][768]  bf16  12.6MB
    u16* Wqkvt  = (u16*)(ws + 100663296);  // [2304][768]  bf16   3.5MB
    u16* W1t    = (u16*)(ws + 104202240);  // [3072][768]  bf16   4.7MB
    u16* W2t    = (u16*)(ws + 108920832);  // [768][3072]  bf16   4.7MB
    u16* Wot    = (u16*)(ws + 113639424);  // [768][768]   bf16   1.2MB
    u16* Vt     = (u16*)(ws + 114819072);  // [96][64][1024] bf16 12.6MB (dead after attn)

    dim3 tb(32, 8);
    transpose_bf16<<<dim3(24, 24), tb, 0, stream>>>(Wq, Wqkvt, 768, 768);
    transpose_bf16<<<dim3(24, 24), tb, 0, stream>>>(Wk, Wqkvt + 768 * 768, 768, 768);
    transpose_bf16<<<dim3(24, 24), tb, 0, stream>>>(Wv, Wqkvt + 2 * 768 * 768, 768, 768);
    transpose_bf16<<<dim3(24, 24), tb, 0, stream>>>(Wo, Wot, 768, 768);
    transpose_bf16<<<dim3(96, 24), tb, 0, stream>>>(W1, W1t, 768, 3072);
    transpose_bf16<<<dim3(24, 96), tb, 0, stream>>>(W2, W2t, 3072, 768);

    // h = LN1(x)
    ln_kernel<<<8192, 256, 0, stream>>>(x, g1, be1, h_bf);
    // qkv = h @ [Wq|Wk|Wv]  (bf16 out)
    gemm_k32<<<dim3(18, 64), 256, 0, stream>>>(h_bf, Wqkvt, nullptr, nullptr, nullptr, qkv_bf, 2304, 768, 0);
    // Vt = per-head transpose of V
    vt_kernel<<<dim3(32, 2, 96), tb, 0, stream>>>(qkv_bf, Vt);
    // o = causal-softmax(q k^T * 768^-.5) v  (bf16 out)
    attn_mfma<<<dim3(16, 96), 256, 0, stream>>>(qkv_bf, Vt, o_bf);
    // x2 = x + o @ Wo + bo
    gemm_k32<<<dim3(6, 64), 256, 0, stream>>>(o_bf, Wot, bo, x, x2, nullptr, 768, 768, 0);
    // h = LN2(x2)
    ln_kernel<<<8192, 256, 0, stream>>>(x2, g2, be2, h_bf);
    // ff1 = gelu(h @ W1 + b1)  (bf16 out)
    gemm_k32<<<dim3(24, 64), 256, 0, stream>>>(h_bf, W1t, b1, nullptr, nullptr, ff1_bf, 3072, 768, 1);
    // out = x2 + ff1 @ W2 + b2
    gemm_k32<<<dim3(6, 64), 256, 0, stream>>>(ff1_bf, W2t, b2, x2, out, nullptr, 768, 3072, 0);
}

// Round 10
// 370.244 us; speedup vs baseline: 1.1229x; 1.0099x over previous
//
#include <hip/hip_runtime.h>
#include <math.h>
#include <stdint.h>

typedef unsigned short u16;
typedef unsigned int u32;
typedef __attribute__((ext_vector_type(8))) __bf16 bf16x8;
typedef __attribute__((ext_vector_type(4))) float f32x4;

#define AS1 __attribute__((address_space(1)))
#define AS3 __attribute__((address_space(3)))

__device__ __forceinline__ void stage16(const void* g, void* l) {
    __builtin_amdgcn_global_load_lds((const AS1 void*)(uintptr_t)g,
                                     (AS3 void*)(uintptr_t)l, 16, 0, 0);
}

__device__ __forceinline__ u16 f2bf(float f) {
    u32 u = __float_as_uint(f);
    u += 0x7fffu + ((u >> 16) & 1u);
    return (u16)(u >> 16);
}

// ---------------- LayerNorm: 256 thr per row of 768, wave-shfl reduce, bf16 out ----------------
__global__ __launch_bounds__(256) void ln_kernel(const float* __restrict__ x,
                                                 const float* __restrict__ g,
                                                 const float* __restrict__ b,
                                                 u16* __restrict__ out) {
    __shared__ float s8[8];
    int row = blockIdx.x;
    int tid = threadIdx.x;
    const int w = tid >> 6;
    const float* xr = x + (size_t)row * 768;
    float x0 = xr[tid], x1 = xr[tid + 256], x2 = xr[tid + 512];

    float sum = x0 + x1 + x2;
#pragma unroll
    for (int off = 32; off; off >>= 1) sum += __shfl_xor(sum, off);
    if ((tid & 63) == 0) s8[w] = sum;
    __syncthreads();
    float mu = (s8[0] + s8[1] + s8[2] + s8[3]) * (1.0f / 768.0f);

    float d0 = x0 - mu, d1 = x1 - mu, d2 = x2 - mu;
    float sq = d0 * d0 + d1 * d1 + d2 * d2;
#pragma unroll
    for (int off = 32; off; off >>= 1) sq += __shfl_xor(sq, off);
    if ((tid & 63) == 0) s8[4 + w] = sq;
    __syncthreads();
    float var = (s8[4] + s8[5] + s8[6] + s8[7]) * (1.0f / 768.0f);
    float rs = rsqrtf(var + 1e-5f);

    u16* orow = out + (size_t)row * 768;
    orow[tid]       = f2bf(d0 * rs * g[tid]       + b[tid]);
    orow[tid + 256] = f2bf(d1 * rs * g[tid + 256] + b[tid + 256]);
    orow[tid + 512] = f2bf(d2 * rs * g[tid + 512] + b[tid + 512]);
}

// ---------------- transpose + fp32->bf16 convert: W[K][N] -> Wt[N][K] ----------------
__global__ __launch_bounds__(256) void transpose_bf16(const float* __restrict__ W,
                                                      u16* __restrict__ Wt,
                                                      int K, int N) {
    __shared__ float t[32][33];
    int tx = threadIdx.x, ty = threadIdx.y;
    int n0 = blockIdx.x * 32, k0 = blockIdx.y * 32;
#pragma unroll
    for (int j = 0; j < 32; j += 8)
        t[ty + j][tx] = W[(size_t)(k0 + ty + j) * N + n0 + tx];
    __syncthreads();
#pragma unroll
    for (int j = 0; j < 32; j += 8)
        Wt[(size_t)(n0 + ty + j) * K + k0 + tx] = f2bf(t[tx][ty + j]);
}

// ---- fused 4x 768x768 transpose (Wq,Wk,Wv -> Wqkvt sections; Wo -> Wot) ----
__global__ __launch_bounds__(256) void transpose4_768(const float* __restrict__ Wq,
                                                      const float* __restrict__ Wk,
                                                      const float* __restrict__ Wv,
                                                      const float* __restrict__ Wo,
                                                      u16* __restrict__ Wqkvt,
                                                      u16* __restrict__ Wot) {
    __shared__ float t[32][33];
    const int z = blockIdx.z;
    const float* W = (z == 0) ? Wq : (z == 1) ? Wk : (z == 2) ? Wv : Wo;
    u16* Wt = (z == 3) ? Wot : (Wqkvt + (size_t)z * 768 * 768);
    int tx = threadIdx.x, ty = threadIdx.y;
    int n0 = blockIdx.x * 32, k0 = blockIdx.y * 32;
#pragma unroll
    for (int j = 0; j < 32; j += 8)
        t[ty + j][tx] = W[(size_t)(k0 + ty + j) * 768 + n0 + tx];
    __syncthreads();
#pragma unroll
    for (int j = 0; j < 32; j += 8)
        Wt[(size_t)(n0 + ty + j) * 768 + k0 + tx] = f2bf(t[tx][ty + j]);
}

// ---------------- V transpose: qkv v-region [8192][2304] -> Vt[96][64][1024] ----------------
__global__ __launch_bounds__(256) void vt_kernel(const u16* __restrict__ qkv,
                                                 u16* __restrict__ Vt) {
    __shared__ u16 t[32][34];
    const int tx = threadIdx.x, ty = threadIdx.y;
    const int s0 = blockIdx.x * 32, d0 = blockIdx.y * 32, bh = blockIdx.z;
    const int b = bh / 12, h = bh % 12;
#pragma unroll
    for (int j = 0; j < 32; j += 8)
        t[ty + j][tx] = qkv[((size_t)(b * 1024) + s0 + ty + j) * 2304 + 1536 + h * 64 + d0 + tx];
    __syncthreads();
#pragma unroll
    for (int j = 0; j < 32; j += 8)
        Vt[((size_t)bh * 64 + d0 + ty + j) * 1024 + s0 + tx] = t[tx][ty + j];
}

// ---------------- bf16 MFMA GEMM: 128^2, BK=32, triple buffer, 2-deep, unroll-3 ----------------
// A: [M][K] bf16 row-major. Bt: [N][K] bf16 row-major. Requires (K/32) % 3 == 0.
// 4 waves (2x2), wave = 64x64. LDS 3 x 16KB = 48KB -> 3 blocks/CU.
// Rows 64B; byte XOR ((row>>1)&3)<<4 (16-row fragment read = 2-way/bank, free).
// Unrolled by 3 so buffer pointers are compile-time -> ds_read addrs loop-invariant.
__global__ __launch_bounds__(256, 3) void gemm_k32(
    const u16* __restrict__ A, const u16* __restrict__ Bt,
    const float* __restrict__ bias, const float* __restrict__ res,
    float* __restrict__ outF, u16* __restrict__ outB,
    int N, int K, int act) {
    __shared__ char lds[49152];
    const int tid = threadIdx.x, lane = tid & 63, wid = tid >> 6;
    const int l15 = lane & 15, lk = lane >> 4;
    const int wrow = (wid >> 1) * 64, wcol = (wid & 1) * 64;

    // bijective XCD swizzle (all launch grids have nwg % 8 == 0)
    int wg = blockIdx.y * gridDim.x + blockIdx.x;
    const int nwg = gridDim.x * gridDim.y;
    wg = (wg & 7) * (nwg >> 3) + (wg >> 3);
    const int brow = (wg / gridDim.x) * 128;
    const int bcol = (wg % gridDim.x) * 128;

    const size_t K2 = (size_t)K * 2;
    const char* Abase = (const char*)A + (size_t)brow * K2;
    const char* Bbase = (const char*)Bt + (size_t)bcol * K2;

    int srow[2], scol[2];
#pragma unroll
    for (int j = 0; j < 2; ++j) {
        const int L = j * 4096 + tid * 16;
        srow[j] = L >> 6;
        scol[j] = (L & 63) ^ (((srow[j] >> 1) & 3) << 4);
    }

    const int nt = K >> 5;  // 24 or 96: divisible by 3

    auto stage_tile = [&](int t, char* dst) {
#pragma unroll
        for (int j = 0; j < 2; ++j) {
            const size_t off = (size_t)srow[j] * K2 + (size_t)t * 64 + scol[j];
            stage16(Abase + off, dst + j * 4096 + tid * 16);
            stage16(Bbase + off, dst + 8192 + j * 4096 + tid * 16);
        }
    };

    f32x4 acc[4][4] = {};

    stage_tile(0, lds);
    stage_tile(1, lds + 16384);

    auto iter = [&](int t, char* buf, char* nxt) {
        if (t + 1 < nt) asm volatile("s_waitcnt vmcnt(4)\n\ts_barrier" ::: "memory");
        else            asm volatile("s_waitcnt vmcnt(0)\n\ts_barrier" ::: "memory");
        __builtin_amdgcn_sched_barrier(0);

        if (t + 2 < nt) stage_tile(t + 2, nxt);

        const char* As = buf;
        const char* Bs = buf + 8192;
        bf16x8 af[4], bfv[4];
#pragma unroll
        for (int m = 0; m < 4; ++m) {
            const int row = wrow + m * 16 + l15;
            af[m] = *(const bf16x8*)(As + row * 64 +
                                     ((lk * 16) ^ (((row >> 1) & 3) << 4)));
        }
#pragma unroll
        for (int n = 0; n < 4; ++n) {
            const int row = wcol + n * 16 + l15;
            bfv[n] = *(const bf16x8*)(Bs + row * 64 +
                                      ((lk * 16) ^ (((row >> 1) & 3) << 4)));
        }
        __builtin_amdgcn_s_setprio(1);
#pragma unroll
        for (int m = 0; m < 4; ++m)
#pragma unroll
            for (int n = 0; n < 4; ++n)
                acc[m][n] = __builtin_amdgcn_mfma_f32_16x16x32_bf16(af[m], bfv[n], acc[m][n], 0, 0, 0);
        __builtin_amdgcn_s_setprio(0);
    };

    for (int t = 0; t < nt; t += 3) {
        iter(t,     lds,         lds + 32768);
        iter(t + 1, lds + 16384, lds);
        iter(t + 2, lds + 32768, lds + 16384);
    }

#pragma unroll
    for (int m = 0; m < 4; ++m)
#pragma unroll
        for (int n = 0; n < 4; ++n)
#pragma unroll
            for (int r = 0; r < 4; ++r) {
                int row = brow + wrow + m * 16 + lk * 4 + r;
                int col = bcol + wcol + n * 16 + l15;
                float v = acc[m][n][r];
                if (bias) v += bias[col];
                if (act) v = 0.5f * v * (1.0f + erff(v * 0.70710678118654752f));
                if (res) v += res[(size_t)row * N + col];
                if (outB) outB[(size_t)row * N + col] = f2bf(v);
                else outF[(size_t)row * N + col] = v;
            }
}

// ---------------- MFMA flash attention, pipelined gload_lds staging + defer-rescale ----------------
// qkv bf16 [8192][2304]; Vt bf16 [96][64][1024].
// Block: 64 q-rows x one (b,h). 4 waves, wave w owns q-rows 16w..16w+15.
// LDS: dbuf { K [64s][64d] 8KB + Vt [64d][64s] 8KB } x2 = 32KB, P 4x2KB = 40KB.
__global__ __launch_bounds__(256) void attn_mfma(const u16* __restrict__ qkv,
                                                 const u16* __restrict__ Vt,
                                                 u16* __restrict__ obf) {
    __shared__ char lds[40960];
    const int tid = threadIdx.x, lane = tid & 63, w = tid >> 6;
    const int g = lane >> 4, l15 = lane & 15;

    int wg = blockIdx.y * gridDim.x + blockIdx.x;
    const int nwg = gridDim.x * gridDim.y;
    wg = (wg & 7) * (nwg >> 3) + (wg >> 3);
    const int qb = 15 - (wg & 15);          // heavy tiles first within each chunk
    const int bh = wg >> 4;
    const int h = bh % 12, b = bh / 12;
    const int t0 = qb * 64;
    const float scale = 0.03608439182435161f;  // 768^-0.5 (C, not hs, per reference)

    // Q fragments (A-operand) in registers
    const size_t qrow = ((size_t)b * 1024 + t0 + 16 * w + l15) * 2304 + h * 64;
    const bf16x8 qf0 = *(const bf16x8*)(qkv + qrow + 8 * g);
    const bf16x8 qf1 = *(const bf16x8*)(qkv + qrow + 8 * g + 32);

    // staging source pointers (pre-swizzled): this thread covers rows r0, r0+8
    const int sub = ((lane & 7) * 16) ^ ((lane >> 3) << 4);
    const int r0 = 16 * w + (lane >> 3);
    const char* kSrc = (const char*)qkv + ((size_t)(b * 1024 + r0) * 2304 + 768 + h * 64) * 2 + sub;
    const char* vSrc = (const char*)Vt + ((size_t)(bh * 64 + r0) * 1024) * 2 + sub;
    const int dstOff = 2 * w * 1024 + lane * 16;

    // prologue: stage tile 0 into buf 0, drain
    stage16(kSrc,            lds + dstOff);
    stage16(kSrc + 8 * 4608, lds + dstOff + 1024);
    stage16(vSrc,            lds + 8192 + dstOff);
    stage16(vSrc + 8 * 2048, lds + 8192 + dstOff + 1024);
    kSrc += 64 * 4608; vSrc += 128;
    __syncthreads();

    const int swzA = (l15 & 7) << 4;
    float m_r[4] = {-1e30f, -1e30f, -1e30f, -1e30f};
    float l_r[4] = {0.f, 0.f, 0.f, 0.f};
    f32x4 oacc[4] = {};
    char* Pw = lds + 32768 + w * 2048;

    for (int c = 0; c <= qb; ++c) {
        if (c < qb) {
            char* dst = lds + ((c + 1) & 1) * 16384;
            stage16(kSrc,            dst + dstOff);
            stage16(kSrc + 8 * 4608, dst + dstOff + 1024);
            stage16(vSrc,            dst + 8192 + dstOff);
            stage16(vSrc + 8 * 2048, dst + 8192 + dstOff + 1024);
            kSrc += 64 * 4608; vSrc += 128;
            asm volatile("s_waitcnt vmcnt(4)\n\ts_barrier" ::: "memory");
        } else {
            asm volatile("s_waitcnt vmcnt(0)\n\ts_barrier" ::: "memory");
        }
        __builtin_amdgcn_sched_barrier(0);

        const char* bufK = lds + (c & 1) * 16384;
        const char* bufV = bufK + 8192;

        // S = Q K^T : D[q=4g+r][s=l15+16st]
        f32x4 sacc[4] = {};
#pragma unroll
        for (int st = 0; st < 4; ++st) {
            const char* krow = bufK + (l15 + 16 * st) * 128;
            const bf16x8 kf0 = *(const bf16x8*)(krow + ((16 * g) ^ swzA));
            const bf16x8 kf1 = *(const bf16x8*)(krow + ((16 * g + 64) ^ swzA));
            sacc[st] = __builtin_amdgcn_mfma_f32_16x16x32_bf16(qf0, kf0, sacc[st], 0, 0, 0);
            sacc[st] = __builtin_amdgcn_mfma_f32_16x16x32_bf16(qf1, kf1, sacc[st], 0, 0, 0);
        }

        const bool diag = (c == qb);
#pragma unroll
        for (int r = 0; r < 4; ++r) {
            float sv0 = sacc[0][r] * scale, sv1 = sacc[1][r] * scale;
            float sv2 = sacc[2][r] * scale, sv3 = sacc[3][r] * scale;
            if (diag) {
                const int trel = 16 * w + 4 * g + r;
                if (l15 +  0 > trel) sv0 = -1e30f;
                if (l15 + 16 > trel) sv1 = -1e30f;
                if (l15 + 32 > trel) sv2 = -1e30f;
                if (l15 + 48 > trel) sv3 = -1e30f;
            }
            float mx = fmaxf(fmaxf(sv0, sv1), fmaxf(sv2, sv3));
#pragma unroll
            for (int off = 1; off < 16; off <<= 1) mx = fmaxf(mx, __shfl_xor(mx, off));
            // defer-rescale (T13): only pay corr-exp + O/l rescale when max grows.
            // Branch is uniform within each 16-lane group (mx, m_r group-uniform).
            if (mx > m_r[r]) {
                const float corr = __expf(m_r[r] - mx);
                m_r[r] = mx;
                l_r[r] *= corr;
                oacc[0][r] *= corr; oacc[1][r] *= corr;
                oacc[2][r] *= corr; oacc[3][r] *= corr;
            }
            const float p0 = __expf(sv0 - m_r[r]), p1 = __expf(sv1 - m_r[r]);
            const float p2 = __expf(sv2 - m_r[r]), p3 = __expf(sv3 - m_r[r]);
            float ps = p0 + p1 + p2 + p3;
#pragma unroll
            for (int off = 1; off < 16; off <<= 1) ps += __shfl_xor(ps, off);
            l_r[r] += ps;
            const int q = 4 * g + r;
            char* pr = Pw + q * 128;
            const int sw = (q & 7) << 4;
            *(u16*)(pr + ((l15 * 2 +  0) ^ sw)) = f2bf(p0);
            *(u16*)(pr + ((l15 * 2 + 32) ^ sw)) = f2bf(p1);
            *(u16*)(pr + ((l15 * 2 + 64) ^ sw)) = f2bf(p2);
            *(u16*)(pr + ((l15 * 2 + 96) ^ sw)) = f2bf(p3);
        }

        // O += P V : A = P[16q][32s-chunk], B = Vt rows (d-major)
#pragma unroll
        for (int kc = 0; kc < 2; ++kc) {
            const bf16x8 pa = *(const bf16x8*)(Pw + l15 * 128 + ((16 * g + 64 * kc) ^ swzA));
#pragma unroll
            for (int dt = 0; dt < 4; ++dt) {
                const int d = l15 + 16 * dt;
                const bf16x8 vf = *(const bf16x8*)(bufV + d * 128 +
                                   ((16 * g + 64 * kc) ^ ((d & 7) << 4)));
                oacc[dt] = __builtin_amdgcn_mfma_f32_16x16x32_bf16(pa, vf, oacc[dt], 0, 0, 0);
            }
        }
        asm volatile("s_barrier" ::: "memory");  // buffers safe to overwrite
    }

    const size_t orow0 = ((size_t)b * 1024 + t0 + 16 * w) * 768 + h * 64;
#pragma unroll
    for (int r = 0; r < 4; ++r) {
        const float inv = 1.0f / l_r[r];
        const size_t orow = orow0 + (size_t)(4 * g + r) * 768;
#pragma unroll
        for (int dt = 0; dt < 4; ++dt)
            obf[orow + 16 * dt + l15] = f2bf(oacc[dt][r] * inv);
    }
}

extern "C" void kernel_launch(void* const* d_in, const int* in_sizes, int n_in,
                              void* d_out, int out_size, void* d_ws, size_t ws_size,
                              hipStream_t stream) {
    const float* x   = (const float*)d_in[0];
    const float* Wq  = (const float*)d_in[1];
    const float* Wk  = (const float*)d_in[2];
    const float* Wv  = (const float*)d_in[3];
    const float* Wo  = (const float*)d_in[4];
    const float* bo  = (const float*)d_in[5];
    const float* W1  = (const float*)d_in[6];
    const float* b1  = (const float*)d_in[7];
    const float* W2  = (const float*)d_in[8];
    const float* b2  = (const float*)d_in[9];
    const float* g1  = (const float*)d_in[10];
    const float* be1 = (const float*)d_in[11];
    const float* g2  = (const float*)d_in[12];
    const float* be2 = (const float*)d_in[13];
    float* out = (float*)d_out;

    char* ws = (char*)d_ws;
    u16* qkv_bf = (u16*)(ws);              // [8192][2304] bf16  37.7MB (dead after attn)
    u16* ff1_bf = (u16*)(ws);              // [8192][3072] bf16  50.3MB (reuses qkv region)
    float* x2   = (float*)(ws + 50331648); // [8192][768]  f32   25.2MB
    u16* h_bf   = (u16*)(ws + 75497472);   // [8192][768]  bf16  12.6MB
    u16* o_bf   = (u16*)(ws + 88080384);   // [8192][768]  bf16  12.6MB
    u16* Wqkvt  = (u16*)(ws + 100663296);  // [2304][768]  bf16   3.5MB
    u16* W1t    = (u16*)(ws + 104202240);  // [3072][768]  bf16   4.7MB
    u16* W2t    = (u16*)(ws + 108920832);  // [768][3072]  bf16   4.7MB
    u16* Wot    = (u16*)(ws + 113639424);  // [768][768]   bf16   1.2MB
    u16* Vt     = (u16*)(ws + 114819072);  // [96][64][1024] bf16 12.6MB (dead after attn)

    dim3 tb(32, 8);
    transpose4_768<<<dim3(24, 24, 4), tb, 0, stream>>>(Wq, Wk, Wv, Wo, Wqkvt, Wot);
    transpose_bf16<<<dim3(96, 24), tb, 0, stream>>>(W1, W1t, 768, 3072);
    transpose_bf16<<<dim3(24, 96), tb, 0, stream>>>(W2, W2t, 3072, 768);

    // h = LN1(x)
    ln_kernel<<<8192, 256, 0, stream>>>(x, g1, be1, h_bf);
    // qkv = h @ [Wq|Wk|Wv]  (bf16 out)
    gemm_k32<<<dim3(18, 64), 256, 0, stream>>>(h_bf, Wqkvt, nullptr, nullptr, nullptr, qkv_bf, 2304, 768, 0);
    // Vt = per-head transpose of V
    vt_kernel<<<dim3(32, 2, 96), tb, 0, stream>>>(qkv_bf, Vt);
    // o = causal-softmax(q k^T * 768^-.5) v  (bf16 out)
    attn_mfma<<<dim3(16, 96), 256, 0, stream>>>(qkv_bf, Vt, o_bf);
    // x2 = x + o @ Wo + bo
    gemm_k32<<<dim3(6, 64), 256, 0, stream>>>(o_bf, Wot, bo, x, x2, nullptr, 768, 768, 0);
    // h = LN2(x2)
    ln_kernel<<<8192, 256, 0, stream>>>(x2, g2, be2, h_bf);
    // ff1 = gelu(h @ W1 + b1)  (bf16 out)
    gemm_k32<<<dim3(24, 64), 256, 0, stream>>>(h_bf, W1t, b1, nullptr, nullptr, ff1_bf, 3072, 768, 1);
    // out = x2 + ff1 @ W2 + b2
    gemm_k32<<<dim3(6, 64), 256, 0, stream>>>(ff1_bf, W2t, b2, x2, out, nullptr, 768, 3072, 0);
}